// Round 6
// baseline (420.813 us; speedup 1.0000x reference)
//
#include <hip/hip_runtime.h>
#include <hip/hip_bf16.h>
#include <cmath>
#include <cstdint>

typedef short s16x8 __attribute__((ext_vector_type(8)));
typedef unsigned short u16x8 __attribute__((ext_vector_type(8)));
typedef unsigned short u16x4 __attribute__((ext_vector_type(4)));
typedef float f32x4 __attribute__((ext_vector_type(4)));

__device__ __forceinline__ float bf2f(uint16_t u) {
  union { uint32_t i; float f; } c; c.i = ((uint32_t)u) << 16; return c.f;
}
__device__ __forceinline__ uint16_t f2bf(float f) {
  union { float f; uint32_t i; } c; c.f = f;
  return (uint16_t)((c.i + 0x7FFFu + ((c.i >> 16) & 1u)) >> 16);
}
// packed f32x2 -> bf16x2 (RNE), low word = a
__device__ __forceinline__ uint32_t pkbf(float a, float b) {
  union { __hip_bfloat162 h; uint32_t u; } c;
  c.h = __float22bfloat162_rn(float2{a, b});
  return c.u;
}

// exact-GELU via A&S 7.1.26 erf (|err|<1.5e-7; negligible vs bf16 rounding)
__device__ __forceinline__ float gelu_exactf(float v) {
  const float x = v * 0.70710678118654752f;
  const float ax = fabsf(x);
  const float t = 1.0f / (1.0f + 0.3275911f * ax);
  const float poly = ((((1.061405429f * t - 1.453152027f) * t + 1.421413741f) * t
                      - 0.284496736f) * t + 0.254829592f) * t;
  const float e = __expf(-x * x);
  float er = 1.0f - poly * e;
  er = copysignf(er, x);
  return 0.5f * v * (1.0f + er);
}

// async global->LDS, 16B/lane; lane i lands at (uniform base) + 16*i
__device__ __forceinline__ void gload16(const void* g, void* l) {
  __builtin_amdgcn_global_load_lds(
      (const __attribute__((address_space(1))) void*)g,
      (__attribute__((address_space(3))) void*)l, 16, 0, 0);
}

// ---- dtype sniff: bf16 data -> even 16-bit words have sane exponents ----
__device__ __forceinline__ bool sniff_is_bf16(const uint16_t* u16, int64_t n,
                                              int tid, int* s_cnt) {
  int cnt = 0;
#pragma unroll
  for (int j = 0; j < 4; j++) {
    int64_t idx = (((int64_t)(tid * 4 + j)) * 2) % n;
    idx &= ~(int64_t)1;
    uint32_t e = (u16[idx] >> 7) & 0xFF;
    cnt += (e >= 96 && e <= 144) ? 1 : 0;
  }
  if (tid == 0) *s_cnt = 0;
  __syncthreads();
  atomicAdd(s_cnt, cnt);
  __syncthreads();
  return (*s_cnt) * 10 > 1024 * 6;
}

// ------ ONE fused prep dispatch (all paths vectorized, 16B/lane) -----------
// [0,1024): zero d_out(16MB, f32x4 x4); [1024,2048): cvt x; [2048,4096): cvt ctx;
// 4096..4098: biases; [4099,5123): 64x64 transposes Wq/Wk/Wv/Wo;
// [5123,6147): W1; [6147,7171): W2.
__global__ __launch_bounds__(256) void prep_all(
    float* dout,
    const void* xr, const void* cr, const void* bor, const void* b1r, const void* b2r,
    const void* Wq, const void* Wk, const void* Wv, const void* Wo,
    const void* W1, const void* W2,
    uint16_t* xo, uint16_t* co, uint16_t* boo, uint16_t* b1o, uint16_t* b2o,
    uint16_t* WqT, uint16_t* WkT, uint16_t* WvT, uint16_t* WoT,
    uint16_t* W1T, uint16_t* W2T) {
  __shared__ int s_cnt;
  __shared__ uint16_t tile[64][65];
  const int id = blockIdx.x;
  const int tid = threadIdx.x;

  if (id < 1024) {  // zero d_out: 4 x f32x4 per thread
    float* p = dout + ((int64_t)id * 256 + tid) * 4;
#pragma unroll
    for (int i = 0; i < 4; i++)
      *(f32x4*)(p + (int64_t)i * 262144) = (f32x4){0.f, 0.f, 0.f, 0.f};
    return;
  }
  if (id < 4099) {  // vectorized converts
    const void* src; uint16_t* dst; int64_t tot; int64_t base; int nv;
    if (id < 2048)      { src = xr; dst = xo; tot = 4194304; base = (int64_t)(id - 1024) * 4096; nv = 4; }
    else if (id < 4096) { src = cr; dst = co; tot = 8388608; base = (int64_t)(id - 2048) * 4096; nv = 4; }
    else if (id == 4096){ src = bor; dst = boo; tot = 1024; base = 0; nv = 1; }
    else if (id == 4097){ src = b1r; dst = b1o; tot = 4096; base = 0; nv = 4; }
    else                { src = b2r; dst = b2o; tot = 1024; base = 0; nv = 1; }
    const bool is16 = sniff_is_bf16((const uint16_t*)src, tot, tid, &s_cnt);
    if (is16) {  // already bf16: copy 8B/lane
      const uint64_t* s = (const uint64_t*)((const uint16_t*)src + base);
      uint64_t* d = (uint64_t*)(dst + base);
      for (int i = 0; i < nv; i++) d[i * 256 + tid] = s[i * 256 + tid];
    } else {  // fp32 -> bf16: float4 load, packed cvt, 8B store
      const f32x4* s = (const f32x4*)((const float*)src + base);
      uint2* d = (uint2*)(dst + base);
      for (int i = 0; i < nv; i++) {
        f32x4 v = s[i * 256 + tid];
        uint2 o; o.x = pkbf(v[0], v[1]); o.y = pkbf(v[2], v[3]);
        d[i * 256 + tid] = o;
      }
    }
    return;
  }
  // 64x64 fp32->bf16 transposes: in[R][C] -> out[C][R]
  const int t0 = id - 4099;
  const void* src; uint16_t* dst; int R, C, bx, by;
  if (t0 < 1024) {  // Wq/Wk/Wv/Wo, 256 tiles each (16x16)
    const int wsel = t0 >> 8, t = t0 & 255;
    const void* srcs[4] = {Wq, Wk, Wv, Wo};
    uint16_t* dsts[4] = {WqT, WkT, WvT, WoT};
    src = srcs[wsel]; dst = dsts[wsel]; R = 1024; C = 1024; bx = t & 15; by = t >> 4;
  } else if (t0 < 2048) { int t = t0 - 1024; src = W1; dst = W1T; R = 1024; C = 4096; bx = t & 63; by = t >> 6; }
  else                  { int t = t0 - 2048; src = W2; dst = W2T; R = 4096; C = 1024; bx = t & 15; by = t >> 4; }
  const uint16_t* u16 = (const uint16_t*)src;
  const float* f32 = (const float*)src;
  const bool is16 = sniff_is_bf16(u16, (int64_t)R * C, tid, &s_cnt);
  const int c0 = bx * 64, r0 = by * 64;
  // load 16B/lane + transpose-scatter into LDS (b16, <=2-way banks)
  if (is16) {
    const int c8 = (tid & 7) * 8, r = tid >> 3;  // 32 rows/pass, 2 passes
#pragma unroll
    for (int ri = 0; ri < 2; ri++) {
      const int row = r + ri * 32;
      u16x8 v = *(const u16x8*)(u16 + (int64_t)(r0 + row) * C + c0 + c8);
#pragma unroll
      for (int j = 0; j < 8; j++) tile[c8 + j][row] = v[j];
    }
  } else {
    const int c4 = (tid & 15) * 4, r = tid >> 4;  // 16 rows/pass, 4 passes
#pragma unroll
    for (int ri = 0; ri < 4; ri++) {
      const int row = r + ri * 16;
      f32x4 v = *(const f32x4*)(f32 + (int64_t)(r0 + row) * C + c0 + c4);
#pragma unroll
      for (int j = 0; j < 4; j++) tile[c4 + j][row] = f2bf(v[j]);
    }
  }
  __syncthreads();
  // write 16B/lane contiguous
  const int rr8 = (tid & 7) * 8, cc = tid >> 3;
#pragma unroll
  for (int ci = 0; ci < 2; ci++) {
    const int col = cc + ci * 32;
    *(u16x8*)(dst + (int64_t)(c0 + col) * R + r0 + rr8) = *(const u16x8*)&tile[col][rr8];
  }
}

// ---- per-batch V transpose (vectorized): KVb[b*2048+k][1024+c] -> Vt[b][c][k]
// grid (16, 32, 4): 64x64 bf16 tiles, 16B reads + 16B writes.
__global__ __launch_bounds__(256) void vtrans(
    const uint16_t* __restrict__ KVb, uint16_t* __restrict__ Vt) {
  __shared__ uint16_t tile[64][65];
  const int z = blockIdx.z;
  const uint16_t* in = KVb + (int64_t)z * 2048 * 2048 + 1024;  // [2048 k][1024 c] stride 2048
  uint16_t* out = Vt + (int64_t)z * 1024 * 2048;               // [1024 c][2048 k]
  const int tid = threadIdx.x;
  const int c0 = blockIdx.x * 64, k0 = blockIdx.y * 64;
  const int c8 = (tid & 7) * 8, r = tid >> 3;
#pragma unroll
  for (int ri = 0; ri < 2; ri++) {
    const int krow = r + ri * 32;
    u16x8 v = *(const u16x8*)(in + (int64_t)(k0 + krow) * 2048 + c0 + c8);
#pragma unroll
    for (int j = 0; j < 8; j++) tile[c8 + j][krow] = v[j];
  }
  __syncthreads();
  const int k8 = (tid & 7) * 8, cc = tid >> 3;
#pragma unroll
  for (int ci = 0; ci < 2; ci++) {
    const int col = cc + ci * 32;
    *(u16x8*)(out + (int64_t)(c0 + col) * 2048 + k0 + k8) = *(const u16x8*)&tile[col][k8];
  }
}

// ---------------- GEMM v4: BK=64, global_load_lds, XOR chunk swizzle ------
// DBUF=1 (gemm_single): LDS double-buffer, ONE raw s_barrier per K-step,
// vmcnt(0) drains tile t (whose loads overlapped compute(t-1)); stage(t+1)
// issued right after the barrier so HBM latency hides under compute(t).
// Race-safe: every wave passes its own vmcnt(0) before the barrier (tile t
// fully in LDS post-barrier); stage(t+1) is issued only after ALL waves
// passed barrier(t), i.e. after all reads of that buffer (tile t-1) done.
// DBUF=0 (gemm_qkv): original serial 2-barrier loop, (256,4).
#define BM 128
#define BN 128
#define BK 64

enum { EPI_NONE = 0, EPI_BIAS_RES = 1, EPI_BIAS_GELU = 2 };

template <int EPI, int RESF32, int OUTF32, int SPLITK, int DBUF>
__device__ __forceinline__ void gemm_body(
    const uint16_t* __restrict__ A, const uint16_t* __restrict__ Bt,
    void* __restrict__ Cv, const uint16_t* __restrict__ bias,
    const void* __restrict__ resid, int M, int N, int K_total,
    int m0, int n0, int zslice, uint16_t* As, uint16_t* Bs) {
  const int tid = threadIdx.x;
  const int w = tid >> 6, l = tid & 63;
  const int wu = __builtin_amdgcn_readfirstlane(w);
  const int wm = (w >> 1) * 64, wn = (w & 1) * 64;
  const int ls = l & 15, lg = l >> 4;
  const int K = SPLITK ? (K_total >> 1) : K_total;
  const int kof = SPLITK ? zslice * K : 0;

  const int sr = 8 * w + (l >> 3);
  const int koff = (((l & 7) ^ ((l >> 3) & 7)) * 8);
  const uint16_t* Ag = A + (int64_t)(m0 + sr) * K_total + kof + koff;
  const uint16_t* Bg = Bt + (int64_t)(n0 + sr) * K_total + kof + koff;
  const int64_t rstep = (int64_t)32 * K_total;

  f32x4 acc[4][4] = {};

  if constexpr (DBUF) {
    // prologue: tile 0 -> half 0
#pragma unroll
    for (int r = 0; r < 4; r++) {
      gload16(Ag + r * rstep, As + r * 2048 + wu * 512);
      gload16(Bg + r * rstep, Bs + r * 2048 + wu * 512);
    }
    for (int kb = 0; kb < K; kb += BK) {
      const int cur = ((kb >> 6) & 1) * 8192;  // current half (elements)
      const int nxt = 8192 - cur;
      asm volatile("s_waitcnt vmcnt(0)" ::: "memory");
      __builtin_amdgcn_s_barrier();
      __builtin_amdgcn_sched_barrier(0);  // fence: no LDS-read hoist past barrier
      const int kbn = kb + BK;
      if (kbn < K) {
#pragma unroll
        for (int r = 0; r < 4; r++) {
          gload16(Ag + r * rstep + kbn, As + nxt + r * 2048 + wu * 512);
          gload16(Bg + r * rstep + kbn, Bs + nxt + r * 2048 + wu * 512);
        }
      }
#pragma unroll
      for (int kk = 0; kk < 2; kk++) {
        s16x8 af[4], bfr[4];
#pragma unroll
        for (int i = 0; i < 4; i++) {
          const int row = wm + i * 16 + ls;
          af[i] = *(const s16x8*)&As[cur + row * 64 + (((kk * 4 + lg) ^ (ls & 7)) * 8)];
        }
#pragma unroll
        for (int j = 0; j < 4; j++) {
          const int row = wn + j * 16 + ls;
          bfr[j] = *(const s16x8*)&Bs[cur + row * 64 + (((kk * 4 + lg) ^ (ls & 7)) * 8)];
        }
#pragma unroll
        for (int i = 0; i < 4; i++)
#pragma unroll
          for (int j = 0; j < 4; j++)
            acc[i][j] = __builtin_amdgcn_mfma_f32_16x16x32_bf16(af[i], bfr[j], acc[i][j], 0, 0, 0);
      }
    }
  } else {
    uint16_t* lA = As + wu * 512;
    uint16_t* lB = Bs + wu * 512;
    for (int kb = 0; kb < K; kb += BK) {
      __syncthreads();
#pragma unroll
      for (int r = 0; r < 4; r++) {
        gload16(Ag + r * rstep + kb, lA + r * 2048);
        gload16(Bg + r * rstep + kb, lB + r * 2048);
      }
      __syncthreads();
#pragma unroll
      for (int kk = 0; kk < 2; kk++) {
        s16x8 af[4], bfr[4];
#pragma unroll
        for (int i = 0; i < 4; i++) {
          const int row = wm + i * 16 + ls;
          af[i] = *(const s16x8*)&As[row * 64 + (((kk * 4 + lg) ^ (ls & 7)) * 8)];
        }
#pragma unroll
        for (int j = 0; j < 4; j++) {
          const int row = wn + j * 16 + ls;
          bfr[j] = *(const s16x8*)&Bs[row * 64 + (((kk * 4 + lg) ^ (ls & 7)) * 8)];
        }
#pragma unroll
        for (int i = 0; i < 4; i++)
#pragma unroll
          for (int j = 0; j < 4; j++)
            acc[i][j] = __builtin_amdgcn_mfma_f32_16x16x32_bf16(af[i], bfr[j], acc[i][j], 0, 0, 0);
      }
    }
  }

#pragma unroll
  for (int i = 0; i < 4; i++) {
#pragma unroll
    for (int rr = 0; rr < 4; rr++) {
      const int64_t row = m0 + wm + i * 16 + lg * 4 + rr;
#pragma unroll
      for (int j = 0; j < 4; j++) {
        const int col = n0 + wn + j * 16 + ls;
        float v = acc[i][j][rr];
        if (EPI == EPI_BIAS_RES) {
          if (!SPLITK || zslice == 0) {
            const float rv = RESF32 ? ((const float*)resid)[row * N + col]
                                    : bf2f(((const uint16_t*)resid)[row * N + col]);
            v += bf2f(bias[col]) + rv;
          }
        } else if (EPI == EPI_BIAS_GELU) {
          v += bf2f(bias[col]);
          v = gelu_exactf(v);  // exact GELU, fast erf
        }
        if (SPLITK)
          atomicAdd((float*)Cv + row * N + col, v);
        else if (OUTF32)
          ((float*)Cv)[row * N + col] = v;
        else
          ((uint16_t*)Cv)[row * N + col] = f2bf(v);
      }
    }
  }
}

template <int EPI, int RESF32, int OUTF32, int SPLITK>
__global__ __launch_bounds__(256, 2) void gemm_single(
    const uint16_t* __restrict__ A, const uint16_t* __restrict__ Bt,
    void* __restrict__ Cv, const uint16_t* __restrict__ bias,
    const void* __restrict__ resid, int M, int N, int K_total) {
  __shared__ alignas(16) uint16_t As[2 * BM * BK];  // 32 KB (double-buffered)
  __shared__ alignas(16) uint16_t Bs[2 * BN * BK];  // 32 KB
  gemm_body<EPI, RESF32, OUTF32, SPLITK, 1>(A, Bt, Cv, bias, resid, M, N, K_total,
                                            blockIdx.x * BM, blockIdx.y * BN,
                                            (int)blockIdx.z, As, Bs);
}

// grouped Q-proj + KV-proj: blocks [0,256) Q, [256,1280) KV. K=1024 both.
// Non-dbuf (deep block queue already keeps occupancy high).
__global__ __launch_bounds__(256, 4) void gemm_qkv(
    const uint16_t* __restrict__ xA, const uint16_t* __restrict__ WqT,
    uint16_t* __restrict__ Qb,
    const uint16_t* __restrict__ ctxA, const uint16_t* __restrict__ KVWt,
    uint16_t* __restrict__ KVb) {
  __shared__ alignas(16) uint16_t As[BM * BK];
  __shared__ alignas(16) uint16_t Bs[BN * BK];
  const int id = blockIdx.x;
  if (id < 256) {
    gemm_body<EPI_NONE, 0, 0, 0, 0>(xA, WqT, Qb, nullptr, nullptr, 4096, 1024, 1024,
                                    (id & 31) * BM, (id >> 5) * BN, 0, As, Bs);
  } else {
    const int t = id - 256;
    gemm_body<EPI_NONE, 0, 0, 0, 0>(ctxA, KVWt, KVb, nullptr, nullptr, 8192, 2048, 1024,
                                    (t & 63) * BM, (t >> 6) * BN, 0, As, Bs);
  }
}

// ---------------- flash cross-attention v7 (round-5 proven) ----------------
#define KLD 72
#define PLD 72

__global__ __launch_bounds__(256, 2) void attn_kernel(
    const uint16_t* __restrict__ Q,   // [B*1024][1024]
    const uint16_t* __restrict__ KV,  // [B*2048][2048]; cols 0..1023 = K
    const uint16_t* __restrict__ Vt,  // [B][1024 (h*64+d)][2048 (key)]
    uint16_t* __restrict__ O) {       // [B*1024][1024]
  __shared__ alignas(16) uint16_t Ks[2][64 * KLD];
  __shared__ alignas(16) uint16_t Vts[2][64 * KLD];
  __shared__ alignas(16) uint16_t Ps[8][16 * PLD];  // [w*2+qq]

  const int tid = threadIdx.x;
  const int w = tid >> 6, l = tid & 63;
  const int ls = l & 15, lg = l >> 4;

  const int blk = blockIdx.x;
  const int bh = blk & 63;   // XCD = bh%8 for all 8 q-blocks of this (b,h)
  const int qb = blk >> 6;   // 0..7
  const int h = bh & 15, b = bh >> 4;

  const int64_t qrow0 = (int64_t)b * 1024 + qb * 128;
  const int hoff = h * 64;
  const uint16_t* Vtb = Vt + (int64_t)b * 1024 * 2048;

  const float sc = 0.125f * 1.4426950408889634f;  // scale * log2(e)

  s16x8 qf[2][2];
#pragma unroll
  for (int qq = 0; qq < 2; qq++)
#pragma unroll
    for (int ks = 0; ks < 2; ks++) {
      s16x8 r = *(const s16x8*)(Q + (qrow0 + w * 32 + qq * 16 + ls) * 1024 + hoff + ks * 32 + lg * 8);
#pragma unroll
      for (int j = 0; j < 8; j++)
        qf[qq][ks][j] = (short)f2bf(bf2f((uint16_t)r[j]) * sc);
    }

  // ones fragment: bf16 1.0 in all 8 slots
  s16x8 onef;
#pragma unroll
  for (int j = 0; j < 8; j++) onef[j] = (short)0x3F80;

  f32x4 oacc[2][4] = {};
  f32x4 lsacc[2] = {};  // row-sum accumulator (ones-MFMA), C-layout

  const int srow = tid >> 3;      // 0..31
  const int sc8 = (tid & 7) * 8;  // 0..56
  const uint16_t* Kg = KV + ((int64_t)b * 2048 + srow) * 2048 + hoff + sc8;
  const uint16_t* Vg = Vtb + (int64_t)(hoff + srow) * 2048 + sc8;

  s16x8 rk0 = *(const s16x8*)(Kg);
  s16x8 rk1 = *(const s16x8*)(Kg + (int64_t)32 * 2048);
  s16x8 rv0 = *(const s16x8*)(Vg);
  s16x8 rv1 = *(const s16x8*)(Vg + (int64_t)32 * 2048);

  for (int kt = 0; kt < 2048; kt += 64) {
    const int bi = (kt >> 6) & 1;
    *(s16x8*)&Ks[bi][srow * KLD + sc8] = rk0;
    *(s16x8*)&Ks[bi][(srow + 32) * KLD + sc8] = rk1;
    *(s16x8*)&Vts[bi][srow * KLD + sc8] = rv0;
    *(s16x8*)&Vts[bi][(srow + 32) * KLD + sc8] = rv1;
    const int ktn = kt + 64;
    if (ktn < 2048) {
      rk0 = *(const s16x8*)(Kg + (int64_t)ktn * 2048);
      rk1 = *(const s16x8*)(Kg + (int64_t)(ktn + 32) * 2048);
      rv0 = *(const s16x8*)(Vg + ktn);
      rv1 = *(const s16x8*)(Vg + ktn + (int64_t)32 * 2048);
    }
    __syncthreads();  // single barrier per tile (dbuf makes pre-write sync redundant)

    f32x4 st[2][4];
    __builtin_amdgcn_s_setprio(1);
#pragma unroll
    for (int jn = 0; jn < 4; jn++) {
      f32x4 z = {0.f, 0.f, 0.f, 0.f};
      st[0][jn] = z; st[1][jn] = z;
#pragma unroll
      for (int ks = 0; ks < 2; ks++) {
        s16x8 kf = *(const s16x8*)&Ks[bi][(jn * 16 + ls) * KLD + ks * 32 + lg * 8];
        st[0][jn] = __builtin_amdgcn_mfma_f32_16x16x32_bf16(kf, qf[0][ks], st[0][jn], 0, 0, 0);
        st[1][jn] = __builtin_amdgcn_mfma_f32_16x16x32_bf16(kf, qf[1][ks], st[1][jn], 0, 0, 0);
      }
    }
    __builtin_amdgcn_s_setprio(0);

#pragma unroll
    for (int qq = 0; qq < 2; qq++)
#pragma unroll
      for (int jn = 0; jn < 4; jn++) {
        const float p0 = exp2f(st[qq][jn][0]);
        const float p1 = exp2f(st[qq][jn][1]);
        const float p2 = exp2f(st[qq][jn][2]);
        const float p3 = exp2f(st[qq][jn][3]);
        uint2 pk; pk.x = pkbf(p0, p1); pk.y = pkbf(p2, p3);
        *(uint2*)&Ps[w * 2 + qq][ls * PLD + jn * 16 + lg * 4] = pk;
      }

    __builtin_amdgcn_s_setprio(1);
#pragma unroll
    for (int ks = 0; ks < 2; ks++) {
      s16x8 pf0 = *(const s16x8*)&Ps[w * 2 + 0][ls * PLD + ks * 32 + lg * 8];
      s16x8 pf1 = *(const s16x8*)&Ps[w * 2 + 1][ls * PLD + ks * 32 + lg * 8];
#pragma unroll
      for (int jn = 0; jn < 4; jn++) {
        s16x8 vf = *(const s16x8*)&Vts[bi][(jn * 16 + ls) * KLD + ks * 32 + lg * 8];
        oacc[0][jn] = __builtin_amdgcn_mfma_f32_16x16x32_bf16(pf0, vf, oacc[0][jn], 0, 0, 0);
        oacc[1][jn] = __builtin_amdgcn_mfma_f32_16x16x32_bf16(pf1, vf, oacc[1][jn], 0, 0, 0);
      }
      // row-sum: D[r][c] = sum_k P[r,k]*1; lane (ls,lg) gets rowsum for
      // q = lg*4+rr -- exactly the epilogue's lane mapping.
      lsacc[0] = __builtin_amdgcn_mfma_f32_16x16x32_bf16(pf0, onef, lsacc[0], 0, 0, 0);
      lsacc[1] = __builtin_amdgcn_mfma_f32_16x16x32_bf16(pf1, onef, lsacc[1], 0, 0, 0);
    }
    __builtin_amdgcn_s_setprio(0);
  }

#pragma unroll
  for (int qq = 0; qq < 2; qq++) {
#pragma unroll
    for (int rr = 0; rr < 4; rr++) {
      const float inv = 1.0f / lsacc[qq][rr];
      const int64_t row = qrow0 + w * 32 + qq * 16 + lg * 4 + rr;
#pragma unroll
      for (int jn = 0; jn < 4; jn++)
        O[row * 1024 + hoff + jn * 16 + ls] = f2bf(oacc[qq][jn][rr] * inv);
    }
  }
}

// ---------------- host ----------------
extern "C" void kernel_launch(void* const* d_in, const int* in_sizes, int n_in,
                              void* d_out, int out_size, void* d_ws, size_t ws_size,
                              hipStream_t stream) {
  const void* x_raw   = d_in[0];
  const void* ctx_raw = d_in[1];
  const void* Wq_raw  = d_in[2];
  const void* Wk_raw  = d_in[3];
  const void* Wv_raw  = d_in[4];
  const void* Wo_raw  = d_in[5];
  const void* bo_raw  = d_in[6];
  const void* W1_raw  = d_in[7];
  const void* b1_raw  = d_in[8];
  const void* W2_raw  = d_in[9];
  const void* b2_raw  = d_in[10];

  const int64_t Mi = 1 << 20;
  uint16_t* ws   = (uint16_t*)d_ws;
  uint16_t* WqT  = ws;                  // [0,1M)
  uint16_t* KVWt = ws + 1 * Mi;         // [1M,3M)  [2048][1024] = [WkT;WvT]
  uint16_t* WoT  = ws + 3 * Mi;         // [3M,4M)
  uint16_t* W1T  = ws + 4 * Mi;         // [4M,8M)   [4096][1024]
  uint16_t* W2T  = ws + 8 * Mi;         // [8M,12M)  [1024][4096]
  uint16_t* bob  = ws + 12 * Mi;
  uint16_t* b1b  = ws + 12 * Mi + 1024;
  uint16_t* b2b  = ws + 12 * Mi + 5120;
  uint16_t* xb   = ws + 13 * Mi;        // [13M,17M) dead after Q-proj
  uint16_t* AO   = ws + 13 * Mi;        // alias xb (born in attention)
  uint16_t* ctxb = ws + 17 * Mi;        // [17M,25M) dead after KV-proj
  uint16_t* Vt   = ws + 17 * Mi;        // alias ctxb (born after KV-proj)
  uint16_t* X1   = ws + 17 * Mi;        // alias Vt (born after attention)
  uint16_t* Qb   = ws + 25 * Mi;        // [25M,29M)
  uint16_t* KVb  = ws + 29 * Mi;        // [29M,45M) [8192][2048]; dead after attn
  uint16_t* Hb   = ws + 29 * Mi;        // alias KVb (born at FF1)
  // peak ws: 45M elements = 90 MB

  const dim3 tb(256);
  // one fused prep dispatch (vectorized): zero + converts + 6 transposes
  prep_all<<<dim3(7171), tb, 0, stream>>>(
      (float*)d_out,
      x_raw, ctx_raw, bo_raw, b1_raw, b2_raw,
      Wq_raw, Wk_raw, Wv_raw, Wo_raw, W1_raw, W2_raw,
      xb, ctxb, bob, b1b, b2b,
      WqT, KVWt, KVWt + Mi, WoT, W1T, W2T);

  // grouped Q-proj + fused KV-proj (1280 blocks)
  gemm_qkv<<<dim3(1280), tb, 0, stream>>>(xb, WqT, Qb, ctxb, KVWt, KVb);

  // per-batch V transpose (vectorized 64x64 tiles)
  vtrans<<<dim3(16, 32, 4), tb, 0, stream>>>(KVb, Vt);

  attn_kernel<<<dim3(512), tb, 0, stream>>>(Qb, KVb, Vt, AO);

  // out-proj + bias + residual(x, fp32 direct)
  gemm_single<EPI_BIAS_RES, 1, 0, 0><<<dim3(32, 8), tb, 0, stream>>>(
      AO, WoT, X1, bob, x_raw, 4096, 1024, 1024);
  // FF1 + bias + exact GELU (fast erf)
  gemm_single<EPI_BIAS_GELU, 0, 0, 0><<<dim3(32, 32), tb, 0, stream>>>(
      X1, W1T, Hb, b1b, nullptr, 4096, 4096, 1024);
  // FF2 + bias + residual(X1), split-K2, fp32 atomics into zeroed d_out
  gemm_single<EPI_BIAS_RES, 0, 1, 1><<<dim3(32, 8, 2), tb, 0, stream>>>(
      Hb, W2T, d_out, b2b, X1, 4096, 1024, 4096);
}

// Round 7
// 418.381 us; speedup vs baseline: 1.0058x; 1.0058x over previous
//
#include <hip/hip_runtime.h>
#include <hip/hip_bf16.h>
#include <cmath>
#include <cstdint>

typedef short s16x8 __attribute__((ext_vector_type(8)));
typedef unsigned short u16x8 __attribute__((ext_vector_type(8)));
typedef unsigned short u16x4 __attribute__((ext_vector_type(4)));
typedef float f32x4 __attribute__((ext_vector_type(4)));

__device__ __forceinline__ float bf2f(uint16_t u) {
  union { uint32_t i; float f; } c; c.i = ((uint32_t)u) << 16; return c.f;
}
__device__ __forceinline__ uint16_t f2bf(float f) {
  union { float f; uint32_t i; } c; c.f = f;
  return (uint16_t)((c.i + 0x7FFFu + ((c.i >> 16) & 1u)) >> 16);
}
// packed f32x2 -> bf16x2 (RNE), low word = a
__device__ __forceinline__ uint32_t pkbf(float a, float b) {
  union { __hip_bfloat162 h; uint32_t u; } c;
  c.h = __float22bfloat162_rn(float2{a, b});
  return c.u;
}

// exact-GELU via A&S 7.1.26 erf (|err|<1.5e-7; negligible vs bf16 rounding)
__device__ __forceinline__ float gelu_exactf(float v) {
  const float x = v * 0.70710678118654752f;
  const float ax = fabsf(x);
  const float t = 1.0f / (1.0f + 0.3275911f * ax);
  const float poly = ((((1.061405429f * t - 1.453152027f) * t + 1.421413741f) * t
                      - 0.284496736f) * t + 0.254829592f) * t;
  const float e = __expf(-x * x);
  float er = 1.0f - poly * e;
  er = copysignf(er, x);
  return 0.5f * v * (1.0f + er);
}

// async global->LDS, 16B/lane; lane i lands at (uniform base) + 16*i
__device__ __forceinline__ void gload16(const void* g, void* l) {
  __builtin_amdgcn_global_load_lds(
      (const __attribute__((address_space(1))) void*)g,
      (__attribute__((address_space(3))) void*)l, 16, 0, 0);
}

// ---- dtype sniff: bf16 data -> even 16-bit words have sane exponents ----
__device__ __forceinline__ bool sniff_is_bf16(const uint16_t* u16, int64_t n,
                                              int tid, int* s_cnt) {
  int cnt = 0;
#pragma unroll
  for (int j = 0; j < 4; j++) {
    int64_t idx = (((int64_t)(tid * 4 + j)) * 2) % n;
    idx &= ~(int64_t)1;
    uint32_t e = (u16[idx] >> 7) & 0xFF;
    cnt += (e >= 96 && e <= 144) ? 1 : 0;
  }
  if (tid == 0) *s_cnt = 0;
  __syncthreads();
  atomicAdd(s_cnt, cnt);
  __syncthreads();
  return (*s_cnt) * 10 > 1024 * 6;
}

// ------ ONE fused prep dispatch (all paths vectorized, 16B/lane) -----------
// [0,1024): zero d_out(16MB, f32x4 x4); [1024,2048): cvt x; [2048,4096): cvt ctx;
// 4096..4098: biases; [4099,5123): 64x64 transposes Wq/Wk/Wv/Wo;
// [5123,6147): W1; [6147,7171): W2.
__global__ __launch_bounds__(256) void prep_all(
    float* dout,
    const void* xr, const void* cr, const void* bor, const void* b1r, const void* b2r,
    const void* Wq, const void* Wk, const void* Wv, const void* Wo,
    const void* W1, const void* W2,
    uint16_t* xo, uint16_t* co, uint16_t* boo, uint16_t* b1o, uint16_t* b2o,
    uint16_t* WqT, uint16_t* WkT, uint16_t* WvT, uint16_t* WoT,
    uint16_t* W1T, uint16_t* W2T) {
  __shared__ int s_cnt;
  __shared__ uint16_t tile[64][65];
  const int id = blockIdx.x;
  const int tid = threadIdx.x;

  if (id < 1024) {  // zero d_out: 4 x f32x4 per thread
    float* p = dout + ((int64_t)id * 256 + tid) * 4;
#pragma unroll
    for (int i = 0; i < 4; i++)
      *(f32x4*)(p + (int64_t)i * 262144) = (f32x4){0.f, 0.f, 0.f, 0.f};
    return;
  }
  if (id < 4099) {  // vectorized converts
    const void* src; uint16_t* dst; int64_t tot; int64_t base; int nv;
    if (id < 2048)      { src = xr; dst = xo; tot = 4194304; base = (int64_t)(id - 1024) * 4096; nv = 4; }
    else if (id < 4096) { src = cr; dst = co; tot = 8388608; base = (int64_t)(id - 2048) * 4096; nv = 4; }
    else if (id == 4096){ src = bor; dst = boo; tot = 1024; base = 0; nv = 1; }
    else if (id == 4097){ src = b1r; dst = b1o; tot = 4096; base = 0; nv = 4; }
    else                { src = b2r; dst = b2o; tot = 1024; base = 0; nv = 1; }
    const bool is16 = sniff_is_bf16((const uint16_t*)src, tot, tid, &s_cnt);
    if (is16) {  // already bf16: copy 8B/lane
      const uint64_t* s = (const uint64_t*)((const uint16_t*)src + base);
      uint64_t* d = (uint64_t*)(dst + base);
      for (int i = 0; i < nv; i++) d[i * 256 + tid] = s[i * 256 + tid];
    } else {  // fp32 -> bf16: float4 load, packed cvt, 8B store
      const f32x4* s = (const f32x4*)((const float*)src + base);
      uint2* d = (uint2*)(dst + base);
      for (int i = 0; i < nv; i++) {
        f32x4 v = s[i * 256 + tid];
        uint2 o; o.x = pkbf(v[0], v[1]); o.y = pkbf(v[2], v[3]);
        d[i * 256 + tid] = o;
      }
    }
    return;
  }
  // 64x64 fp32->bf16 transposes: in[R][C] -> out[C][R]
  const int t0 = id - 4099;
  const void* src; uint16_t* dst; int R, C, bx, by;
  if (t0 < 1024) {  // Wq/Wk/Wv/Wo, 256 tiles each (16x16)
    const int wsel = t0 >> 8, t = t0 & 255;
    const void* srcs[4] = {Wq, Wk, Wv, Wo};
    uint16_t* dsts[4] = {WqT, WkT, WvT, WoT};
    src = srcs[wsel]; dst = dsts[wsel]; R = 1024; C = 1024; bx = t & 15; by = t >> 4;
  } else if (t0 < 2048) { int t = t0 - 1024; src = W1; dst = W1T; R = 1024; C = 4096; bx = t & 63; by = t >> 6; }
  else                  { int t = t0 - 2048; src = W2; dst = W2T; R = 4096; C = 1024; bx = t & 15; by = t >> 4; }
  const uint16_t* u16 = (const uint16_t*)src;
  const float* f32 = (const float*)src;
  const bool is16 = sniff_is_bf16(u16, (int64_t)R * C, tid, &s_cnt);
  const int c0 = bx * 64, r0 = by * 64;
  // load 16B/lane + transpose-scatter into LDS (b16, <=2-way banks)
  if (is16) {
    const int c8 = (tid & 7) * 8, r = tid >> 3;  // 32 rows/pass, 2 passes
#pragma unroll
    for (int ri = 0; ri < 2; ri++) {
      const int row = r + ri * 32;
      u16x8 v = *(const u16x8*)(u16 + (int64_t)(r0 + row) * C + c0 + c8);
#pragma unroll
      for (int j = 0; j < 8; j++) tile[c8 + j][row] = v[j];
    }
  } else {
    const int c4 = (tid & 15) * 4, r = tid >> 4;  // 16 rows/pass, 4 passes
#pragma unroll
    for (int ri = 0; ri < 4; ri++) {
      const int row = r + ri * 16;
      f32x4 v = *(const f32x4*)(f32 + (int64_t)(r0 + row) * C + c0 + c4);
#pragma unroll
      for (int j = 0; j < 4; j++) tile[c4 + j][row] = f2bf(v[j]);
    }
  }
  __syncthreads();
  // write 16B/lane contiguous
  const int rr8 = (tid & 7) * 8, cc = tid >> 3;
#pragma unroll
  for (int ci = 0; ci < 2; ci++) {
    const int col = cc + ci * 32;
    *(u16x8*)(dst + (int64_t)(c0 + col) * R + r0 + rr8) = *(const u16x8*)&tile[col][rr8];
  }
}

// ---- per-batch V transpose (vectorized): KVb[b*2048+k][1024+c] -> Vt[b][c][k]
// grid (16, 32, 4): 64x64 bf16 tiles, 16B reads + 16B writes.
__global__ __launch_bounds__(256) void vtrans(
    const uint16_t* __restrict__ KVb, uint16_t* __restrict__ Vt) {
  __shared__ uint16_t tile[64][65];
  const int z = blockIdx.z;
  const uint16_t* in = KVb + (int64_t)z * 2048 * 2048 + 1024;  // [2048 k][1024 c] stride 2048
  uint16_t* out = Vt + (int64_t)z * 1024 * 2048;               // [1024 c][2048 k]
  const int tid = threadIdx.x;
  const int c0 = blockIdx.x * 64, k0 = blockIdx.y * 64;
  const int c8 = (tid & 7) * 8, r = tid >> 3;
#pragma unroll
  for (int ri = 0; ri < 2; ri++) {
    const int krow = r + ri * 32;
    u16x8 v = *(const u16x8*)(in + (int64_t)(k0 + krow) * 2048 + c0 + c8);
#pragma unroll
    for (int j = 0; j < 8; j++) tile[c8 + j][krow] = v[j];
  }
  __syncthreads();
  const int k8 = (tid & 7) * 8, cc = tid >> 3;
#pragma unroll
  for (int ci = 0; ci < 2; ci++) {
    const int col = cc + ci * 32;
    *(u16x8*)(out + (int64_t)(c0 + col) * 2048 + k0 + k8) = *(const u16x8*)&tile[col][k8];
  }
}

// ---------------- GEMM v4: BK=64, global_load_lds, XOR chunk swizzle ------
// __launch_bounds__(256,4): 4 blocks/CU (16 waves/CU). Regs: 56 VGPR + 64
// AGPR acc = 120 <= 128/wave; LDS 32KB x 4 = 128 <= 160KB. Cross-block
// overlap hides the per-barrier vmcnt(0) drain (round-4 verified; all
// source-level pipelining variants regressed: rounds 1,2,3,6).
// SPLITK = number of K slices (0/1 = none); slices >0 atomicAdd into a
// pre-zeroed f32 buffer; bias+residual applied only by slice 0.
#define BM 128
#define BN 128
#define BK 64

enum { EPI_NONE = 0, EPI_BIAS_RES = 1, EPI_BIAS_GELU = 2 };

template <int EPI, int RESF32, int OUTF32, int SPLITK>
__device__ __forceinline__ void gemm_body(
    const uint16_t* __restrict__ A, const uint16_t* __restrict__ Bt,
    void* __restrict__ Cv, const uint16_t* __restrict__ bias,
    const void* __restrict__ resid, int M, int N, int K_total,
    int m0, int n0, int zslice, uint16_t* As, uint16_t* Bs) {
  const int tid = threadIdx.x;
  const int w = tid >> 6, l = tid & 63;
  const int wu = __builtin_amdgcn_readfirstlane(w);
  const int wm = (w >> 1) * 64, wn = (w & 1) * 64;
  const int ls = l & 15, lg = l >> 4;
  const int K = (SPLITK > 1) ? (K_total / SPLITK) : K_total;
  const int kof = (SPLITK > 1) ? zslice * K : 0;

  const int sr = 8 * w + (l >> 3);
  const int koff = (((l & 7) ^ ((l >> 3) & 7)) * 8);
  const uint16_t* Ag = A + (int64_t)(m0 + sr) * K_total + kof + koff;
  const uint16_t* Bg = Bt + (int64_t)(n0 + sr) * K_total + kof + koff;
  const int64_t rstep = (int64_t)32 * K_total;

  uint16_t* lA = As + wu * 512;
  uint16_t* lB = Bs + wu * 512;

  f32x4 acc[4][4] = {};

  for (int kb = 0; kb < K; kb += BK) {
    __syncthreads();
#pragma unroll
    for (int r = 0; r < 4; r++) {
      gload16(Ag + r * rstep + kb, lA + r * 2048);
      gload16(Bg + r * rstep + kb, lB + r * 2048);
    }
    __syncthreads();
#pragma unroll
    for (int kk = 0; kk < 2; kk++) {
      s16x8 af[4], bfr[4];
#pragma unroll
      for (int i = 0; i < 4; i++) {
        const int row = wm + i * 16 + ls;
        af[i] = *(const s16x8*)&As[row * 64 + (((kk * 4 + lg) ^ (ls & 7)) * 8)];
      }
#pragma unroll
      for (int j = 0; j < 4; j++) {
        const int row = wn + j * 16 + ls;
        bfr[j] = *(const s16x8*)&Bs[row * 64 + (((kk * 4 + lg) ^ (ls & 7)) * 8)];
      }
#pragma unroll
      for (int i = 0; i < 4; i++)
#pragma unroll
        for (int j = 0; j < 4; j++)
          acc[i][j] = __builtin_amdgcn_mfma_f32_16x16x32_bf16(af[i], bfr[j], acc[i][j], 0, 0, 0);
    }
  }

#pragma unroll
  for (int i = 0; i < 4; i++) {
#pragma unroll
    for (int rr = 0; rr < 4; rr++) {
      const int64_t row = m0 + wm + i * 16 + lg * 4 + rr;
#pragma unroll
      for (int j = 0; j < 4; j++) {
        const int col = n0 + wn + j * 16 + ls;
        float v = acc[i][j][rr];
        if (EPI == EPI_BIAS_RES) {
          if (SPLITK <= 1 || zslice == 0) {
            const float rv = RESF32 ? ((const float*)resid)[row * N + col]
                                    : bf2f(((const uint16_t*)resid)[row * N + col]);
            v += bf2f(bias[col]) + rv;
          }
        } else if (EPI == EPI_BIAS_GELU) {
          v += bf2f(bias[col]);
          v = gelu_exactf(v);  // exact GELU, fast erf
        }
        if (SPLITK > 1)
          atomicAdd((float*)Cv + row * N + col, v);
        else if (OUTF32)
          ((float*)Cv)[row * N + col] = v;
        else
          ((uint16_t*)Cv)[row * N + col] = f2bf(v);
      }
    }
  }
}

template <int EPI, int RESF32, int OUTF32, int SPLITK>
__global__ __launch_bounds__(256, 4) void gemm_single(
    const uint16_t* __restrict__ A, const uint16_t* __restrict__ Bt,
    void* __restrict__ Cv, const uint16_t* __restrict__ bias,
    const void* __restrict__ resid, int M, int N, int K_total) {
  __shared__ alignas(16) uint16_t As[BM * BK];
  __shared__ alignas(16) uint16_t Bs[BN * BK];
  gemm_body<EPI, RESF32, OUTF32, SPLITK>(A, Bt, Cv, bias, resid, M, N, K_total,
                                         blockIdx.x * BM, blockIdx.y * BN,
                                         (int)blockIdx.z, As, Bs);
}

// grouped Q-proj + KV-proj: blocks [0,256) Q, [256,1280) KV. K=1024 both.
__global__ __launch_bounds__(256, 4) void gemm_qkv(
    const uint16_t* __restrict__ xA, const uint16_t* __restrict__ WqT,
    uint16_t* __restrict__ Qb,
    const uint16_t* __restrict__ ctxA, const uint16_t* __restrict__ KVWt,
    uint16_t* __restrict__ KVb) {
  __shared__ alignas(16) uint16_t As[BM * BK];
  __shared__ alignas(16) uint16_t Bs[BN * BK];
  const int id = blockIdx.x;
  if (id < 256) {
    gemm_body<EPI_NONE, 0, 0, 0>(xA, WqT, Qb, nullptr, nullptr, 4096, 1024, 1024,
                                 (id & 31) * BM, (id >> 5) * BN, 0, As, Bs);
  } else {
    const int t = id - 256;
    gemm_body<EPI_NONE, 0, 0, 0>(ctxA, KVWt, KVb, nullptr, nullptr, 8192, 2048, 1024,
                                 (t & 63) * BM, (t >> 6) * BN, 0, As, Bs);
  }
}

// ---------------- flash cross-attention v7 (round-5 proven) ----------------
// dbuf K/V -> one barrier/tile; ones-MFMA row-sum in epilogue lane layout;
// setprio around MFMA clusters (2 independent blocks/CU).
#define KLD 72
#define PLD 72

__global__ __launch_bounds__(256, 2) void attn_kernel(
    const uint16_t* __restrict__ Q,   // [B*1024][1024]
    const uint16_t* __restrict__ KV,  // [B*2048][2048]; cols 0..1023 = K
    const uint16_t* __restrict__ Vt,  // [B][1024 (h*64+d)][2048 (key)]
    uint16_t* __restrict__ O) {       // [B*1024][1024]
  __shared__ alignas(16) uint16_t Ks[2][64 * KLD];
  __shared__ alignas(16) uint16_t Vts[2][64 * KLD];
  __shared__ alignas(16) uint16_t Ps[8][16 * PLD];  // [w*2+qq]

  const int tid = threadIdx.x;
  const int w = tid >> 6, l = tid & 63;
  const int ls = l & 15, lg = l >> 4;

  const int blk = blockIdx.x;
  const int bh = blk & 63;   // XCD = bh%8 for all 8 q-blocks of this (b,h)
  const int qb = blk >> 6;   // 0..7
  const int h = bh & 15, b = bh >> 4;

  const int64_t qrow0 = (int64_t)b * 1024 + qb * 128;
  const int hoff = h * 64;
  const uint16_t* Vtb = Vt + (int64_t)b * 1024 * 2048;

  const float sc = 0.125f * 1.4426950408889634f;  // scale * log2(e)

  s16x8 qf[2][2];
#pragma unroll
  for (int qq = 0; qq < 2; qq++)
#pragma unroll
    for (int ks = 0; ks < 2; ks++) {
      s16x8 r = *(const s16x8*)(Q + (qrow0 + w * 32 + qq * 16 + ls) * 1024 + hoff + ks * 32 + lg * 8);
#pragma unroll
      for (int j = 0; j < 8; j++)
        qf[qq][ks][j] = (short)f2bf(bf2f((uint16_t)r[j]) * sc);
    }

  // ones fragment: bf16 1.0 in all 8 slots
  s16x8 onef;
#pragma unroll
  for (int j = 0; j < 8; j++) onef[j] = (short)0x3F80;

  f32x4 oacc[2][4] = {};
  f32x4 lsacc[2] = {};  // row-sum accumulator (ones-MFMA), C-layout

  const int srow = tid >> 3;      // 0..31
  const int sc8 = (tid & 7) * 8;  // 0..56
  const uint16_t* Kg = KV + ((int64_t)b * 2048 + srow) * 2048 + hoff + sc8;
  const uint16_t* Vg = Vtb + (int64_t)(hoff + srow) * 2048 + sc8;

  s16x8 rk0 = *(const s16x8*)(Kg);
  s16x8 rk1 = *(const s16x8*)(Kg + (int64_t)32 * 2048);
  s16x8 rv0 = *(const s16x8*)(Vg);
  s16x8 rv1 = *(const s16x8*)(Vg + (int64_t)32 * 2048);

  for (int kt = 0; kt < 2048; kt += 64) {
    const int bi = (kt >> 6) & 1;
    *(s16x8*)&Ks[bi][srow * KLD + sc8] = rk0;
    *(s16x8*)&Ks[bi][(srow + 32) * KLD + sc8] = rk1;
    *(s16x8*)&Vts[bi][srow * KLD + sc8] = rv0;
    *(s16x8*)&Vts[bi][(srow + 32) * KLD + sc8] = rv1;
    const int ktn = kt + 64;
    if (ktn < 2048) {
      rk0 = *(const s16x8*)(Kg + (int64_t)ktn * 2048);
      rk1 = *(const s16x8*)(Kg + (int64_t)(ktn + 32) * 2048);
      rv0 = *(const s16x8*)(Vg + ktn);
      rv1 = *(const s16x8*)(Vg + ktn + (int64_t)32 * 2048);
    }
    __syncthreads();  // single barrier per tile (dbuf makes pre-write sync redundant)

    f32x4 st[2][4];
    __builtin_amdgcn_s_setprio(1);
#pragma unroll
    for (int jn = 0; jn < 4; jn++) {
      f32x4 z = {0.f, 0.f, 0.f, 0.f};
      st[0][jn] = z; st[1][jn] = z;
#pragma unroll
      for (int ks = 0; ks < 2; ks++) {
        s16x8 kf = *(const s16x8*)&Ks[bi][(jn * 16 + ls) * KLD + ks * 32 + lg * 8];
        st[0][jn] = __builtin_amdgcn_mfma_f32_16x16x32_bf16(kf, qf[0][ks], st[0][jn], 0, 0, 0);
        st[1][jn] = __builtin_amdgcn_mfma_f32_16x16x32_bf16(kf, qf[1][ks], st[1][jn], 0, 0, 0);
      }
    }
    __builtin_amdgcn_s_setprio(0);

#pragma unroll
    for (int qq = 0; qq < 2; qq++)
#pragma unroll
      for (int jn = 0; jn < 4; jn++) {
        const float p0 = exp2f(st[qq][jn][0]);
        const float p1 = exp2f(st[qq][jn][1]);
        const float p2 = exp2f(st[qq][jn][2]);
        const float p3 = exp2f(st[qq][jn][3]);
        uint2 pk; pk.x = pkbf(p0, p1); pk.y = pkbf(p2, p3);
        *(uint2*)&Ps[w * 2 + qq][ls * PLD + jn * 16 + lg * 4] = pk;
      }

    __builtin_amdgcn_s_setprio(1);
#pragma unroll
    for (int ks = 0; ks < 2; ks++) {
      s16x8 pf0 = *(const s16x8*)&Ps[w * 2 + 0][ls * PLD + ks * 32 + lg * 8];
      s16x8 pf1 = *(const s16x8*)&Ps[w * 2 + 1][ls * PLD + ks * 32 + lg * 8];
#pragma unroll
      for (int jn = 0; jn < 4; jn++) {
        s16x8 vf = *(const s16x8*)&Vts[bi][(jn * 16 + ls) * KLD + ks * 32 + lg * 8];
        oacc[0][jn] = __builtin_amdgcn_mfma_f32_16x16x32_bf16(pf0, vf, oacc[0][jn], 0, 0, 0);
        oacc[1][jn] = __builtin_amdgcn_mfma_f32_16x16x32_bf16(pf1, vf, oacc[1][jn], 0, 0, 0);
      }
      // row-sum: D[r][c] = sum_k P[r,k]*1; lane (ls,lg) gets rowsum for
      // q = lg*4+rr -- exactly the epilogue's lane mapping.
      lsacc[0] = __builtin_amdgcn_mfma_f32_16x16x32_bf16(pf0, onef, lsacc[0], 0, 0, 0);
      lsacc[1] = __builtin_amdgcn_mfma_f32_16x16x32_bf16(pf1, onef, lsacc[1], 0, 0, 0);
    }
    __builtin_amdgcn_s_setprio(0);
  }

#pragma unroll
  for (int qq = 0; qq < 2; qq++) {
#pragma unroll
    for (int rr = 0; rr < 4; rr++) {
      const float inv = 1.0f / lsacc[qq][rr];
      const int64_t row = qrow0 + w * 32 + qq * 16 + lg * 4 + rr;
#pragma unroll
      for (int jn = 0; jn < 4; jn++)
        O[row * 1024 + hoff + jn * 16 + ls] = f2bf(oacc[qq][jn][rr] * inv);
    }
  }
}

// ---------------- host ----------------
extern "C" void kernel_launch(void* const* d_in, const int* in_sizes, int n_in,
                              void* d_out, int out_size, void* d_ws, size_t ws_size,
                              hipStream_t stream) {
  const void* x_raw   = d_in[0];
  const void* ctx_raw = d_in[1];
  const void* Wq_raw  = d_in[2];
  const void* Wk_raw  = d_in[3];
  const void* Wv_raw  = d_in[4];
  const void* Wo_raw  = d_in[5];
  const void* bo_raw  = d_in[6];
  const void* W1_raw  = d_in[7];
  const void* b1_raw  = d_in[8];
  const void* W2_raw  = d_in[9];
  const void* b2_raw  = d_in[10];

  const int64_t Mi = 1 << 20;
  uint16_t* ws   = (uint16_t*)d_ws;
  uint16_t* WqT  = ws;                  // [0,1M)
  uint16_t* KVWt = ws + 1 * Mi;         // [1M,3M)  [2048][1024] = [WkT;WvT]
  uint16_t* WoT  = ws + 3 * Mi;         // [3M,4M)
  uint16_t* W1T  = ws + 4 * Mi;         // [4M,8M)   [4096][1024]
  uint16_t* W2T  = ws + 8 * Mi;         // [8M,12M)  [1024][4096]
  uint16_t* bob  = ws + 12 * Mi;
  uint16_t* b1b  = ws + 12 * Mi + 1024;
  uint16_t* b2b  = ws + 12 * Mi + 5120;
  uint16_t* xb   = ws + 13 * Mi;        // [13M,17M) dead after Q-proj
  uint16_t* AO   = ws + 13 * Mi;        // alias xb (born in attention)
  uint16_t* ctxb = ws + 17 * Mi;        // [17M,25M) dead after KV-proj
  uint16_t* Vt   = ws + 17 * Mi;        // alias ctxb (born after KV-proj)
  uint16_t* X1   = ws + 17 * Mi;        // alias Vt (born after attention)
  uint16_t* Qb   = ws + 25 * Mi;        // [25M,29M)
  uint16_t* KVb  = ws + 29 * Mi;        // [29M,45M) [8192][2048]; dead after attn
  uint16_t* Hb   = ws + 29 * Mi;        // alias KVb (born at FF1)
  // peak ws: 45M elements = 90 MB

  const dim3 tb(256);
  // one fused prep dispatch (vectorized): zero + converts + 6 transposes
  prep_all<<<dim3(7171), tb, 0, stream>>>(
      (float*)d_out,
      x_raw, ctx_raw, bo_raw, b1_raw, b2_raw,
      Wq_raw, Wk_raw, Wv_raw, Wo_raw, W1_raw, W2_raw,
      xb, ctxb, bob, b1b, b2b,
      WqT, KVWt, KVWt + Mi, WoT, W1T, W2T);

  // grouped Q-proj + fused KV-proj (1280 blocks)
  gemm_qkv<<<dim3(1280), tb, 0, stream>>>(xb, WqT, Qb, ctxb, KVWt, KVb);

  // per-batch V transpose (vectorized 64x64 tiles)
  vtrans<<<dim3(16, 32, 4), tb, 0, stream>>>(KVb, Vt);

  attn_kernel<<<dim3(512), tb, 0, stream>>>(Qb, KVb, Vt, AO);

  // out-proj + bias + residual(x, fp32 direct)
  gemm_single<EPI_BIAS_RES, 1, 0, 0><<<dim3(32, 8), tb, 0, stream>>>(
      AO, WoT, X1, bob, x_raw, 4096, 1024, 1024);
  // FF1 + bias + exact GELU (fast erf)
  gemm_single<EPI_BIAS_GELU, 0, 0, 0><<<dim3(32, 32), tb, 0, stream>>>(
      X1, W1T, Hb, b1b, nullptr, 4096, 4096, 1024);
  // FF2 + bias + residual(X1): split-K4 -> 1024 blocks = 4 blocks/CU
  // (was split-K2 = 512 blocks = 2/CU); extra atomic RMW is L2-resident
  // (d_out 16MB f32 << 32MB aggregate L2).
  gemm_single<EPI_BIAS_RES, 0, 1, 4><<<dim3(32, 8, 4), tb, 0, stream>>>(
      Hb, W2T, d_out, b2b, X1, 4096, 1024, 4096);
}

// Round 8
// 376.903 us; speedup vs baseline: 1.1165x; 1.1101x over previous
//
#include <hip/hip_runtime.h>
#include <hip/hip_bf16.h>
#include <cmath>
#include <cstdint>

typedef short s16x8 __attribute__((ext_vector_type(8)));
typedef unsigned short u16x8 __attribute__((ext_vector_type(8)));
typedef unsigned short u16x4 __attribute__((ext_vector_type(4)));
typedef float f32x4 __attribute__((ext_vector_type(4)));

__device__ __forceinline__ float bf2f(uint16_t u) {
  union { uint32_t i; float f; } c; c.i = ((uint32_t)u) << 16; return c.f;
}
__device__ __forceinline__ uint16_t f2bf(float f) {
  union { float f; uint32_t i; } c; c.f = f;
  return (uint16_t)((c.i + 0x7FFFu + ((c.i >> 16) & 1u)) >> 16);
}
// packed f32x2 -> bf16x2 (RNE), low word = a
__device__ __forceinline__ uint32_t pkbf(float a, float b) {
  union { __hip_bfloat162 h; uint32_t u; } c;
  c.h = __float22bfloat162_rn(float2{a, b});
  return c.u;
}

// exact-GELU via A&S 7.1.26 erf (|err|<1.5e-7; negligible vs bf16 rounding)
__device__ __forceinline__ float gelu_exactf(float v) {
  const float x = v * 0.70710678118654752f;
  const float ax = fabsf(x);
  const float t = 1.0f / (1.0f + 0.3275911f * ax);
  const float poly = ((((1.061405429f * t - 1.453152027f) * t + 1.421413741f) * t
                      - 0.284496736f) * t + 0.254829592f) * t;
  const float e = __expf(-x * x);
  float er = 1.0f - poly * e;
  er = copysignf(er, x);
  return 0.5f * v * (1.0f + er);
}

// async global->LDS, 16B/lane; lane i lands at (uniform base) + 16*i
__device__ __forceinline__ void gload16(const void* g, void* l) {
  __builtin_amdgcn_global_load_lds(
      (const __attribute__((address_space(1))) void*)g,
      (__attribute__((address_space(3))) void*)l, 16, 0, 0);
}

// ---- dtype sniff: bf16 data -> even 16-bit words have sane exponents ----
__device__ __forceinline__ bool sniff_is_bf16(const uint16_t* u16, int64_t n,
                                              int tid, int* s_cnt) {
  int cnt = 0;
#pragma unroll
  for (int j = 0; j < 4; j++) {
    int64_t idx = (((int64_t)(tid * 4 + j)) * 2) % n;
    idx &= ~(int64_t)1;
    uint32_t e = (u16[idx] >> 7) & 0xFF;
    cnt += (e >= 96 && e <= 144) ? 1 : 0;
  }
  if (tid == 0) *s_cnt = 0;
  __syncthreads();
  atomicAdd(s_cnt, cnt);
  __syncthreads();
  return (*s_cnt) * 10 > 1024 * 6;
}

// ------ ONE fused prep dispatch (all paths vectorized, 16B/lane) -----------
// [0,1024): cvt x; [1024,3072): cvt ctx; 3072..3074: biases;
// [3075,4099): 64x64 transposes Wq/Wk/Wv/Wo; [4099,5123): W1; [5123,6147): W2.
// (No d_out zeroing: FF2 is no-atomic now, d_out is plain-stored.)
__global__ __launch_bounds__(256) void prep_all(
    const void* xr, const void* cr, const void* bor, const void* b1r, const void* b2r,
    const void* Wq, const void* Wk, const void* Wv, const void* Wo,
    const void* W1, const void* W2,
    uint16_t* xo, uint16_t* co, uint16_t* boo, uint16_t* b1o, uint16_t* b2o,
    uint16_t* WqT, uint16_t* WkT, uint16_t* WvT, uint16_t* WoT,
    uint16_t* W1T, uint16_t* W2T) {
  __shared__ int s_cnt;
  __shared__ uint16_t tile[64][65];
  const int id = blockIdx.x;
  const int tid = threadIdx.x;

  if (id < 3075) {  // vectorized converts
    const void* src; uint16_t* dst; int64_t tot; int64_t base; int nv;
    if (id < 1024)      { src = xr; dst = xo; tot = 4194304; base = (int64_t)id * 4096; nv = 4; }
    else if (id < 3072) { src = cr; dst = co; tot = 8388608; base = (int64_t)(id - 1024) * 4096; nv = 4; }
    else if (id == 3072){ src = bor; dst = boo; tot = 1024; base = 0; nv = 1; }
    else if (id == 3073){ src = b1r; dst = b1o; tot = 4096; base = 0; nv = 4; }
    else                { src = b2r; dst = b2o; tot = 1024; base = 0; nv = 1; }
    const bool is16 = sniff_is_bf16((const uint16_t*)src, tot, tid, &s_cnt);
    if (is16) {  // already bf16: copy 8B/lane
      const uint64_t* s = (const uint64_t*)((const uint16_t*)src + base);
      uint64_t* d = (uint64_t*)(dst + base);
      for (int i = 0; i < nv; i++) d[i * 256 + tid] = s[i * 256 + tid];
    } else {  // fp32 -> bf16: float4 load, packed cvt, 8B store
      const f32x4* s = (const f32x4*)((const float*)src + base);
      uint2* d = (uint2*)(dst + base);
      for (int i = 0; i < nv; i++) {
        f32x4 v = s[i * 256 + tid];
        uint2 o; o.x = pkbf(v[0], v[1]); o.y = pkbf(v[2], v[3]);
        d[i * 256 + tid] = o;
      }
    }
    return;
  }
  // 64x64 fp32->bf16 transposes: in[R][C] -> out[C][R]
  const int t0 = id - 3075;
  const void* src; uint16_t* dst; int R, C, bx, by;
  if (t0 < 1024) {  // Wq/Wk/Wv/Wo, 256 tiles each (16x16)
    const int wsel = t0 >> 8, t = t0 & 255;
    const void* srcs[4] = {Wq, Wk, Wv, Wo};
    uint16_t* dsts[4] = {WqT, WkT, WvT, WoT};
    src = srcs[wsel]; dst = dsts[wsel]; R = 1024; C = 1024; bx = t & 15; by = t >> 4;
  } else if (t0 < 2048) { int t = t0 - 1024; src = W1; dst = W1T; R = 1024; C = 4096; bx = t & 63; by = t >> 6; }
  else                  { int t = t0 - 2048; src = W2; dst = W2T; R = 4096; C = 1024; bx = t & 15; by = t >> 4; }
  const uint16_t* u16 = (const uint16_t*)src;
  const float* f32 = (const float*)src;
  const bool is16 = sniff_is_bf16(u16, (int64_t)R * C, tid, &s_cnt);
  const int c0 = bx * 64, r0 = by * 64;
  // load 16B/lane + transpose-scatter into LDS (b16, <=2-way banks)
  if (is16) {
    const int c8 = (tid & 7) * 8, r = tid >> 3;  // 32 rows/pass, 2 passes
#pragma unroll
    for (int ri = 0; ri < 2; ri++) {
      const int row = r + ri * 32;
      u16x8 v = *(const u16x8*)(u16 + (int64_t)(r0 + row) * C + c0 + c8);
#pragma unroll
      for (int j = 0; j < 8; j++) tile[c8 + j][row] = v[j];
    }
  } else {
    const int c4 = (tid & 15) * 4, r = tid >> 4;  // 16 rows/pass, 4 passes
#pragma unroll
    for (int ri = 0; ri < 4; ri++) {
      const int row = r + ri * 16;
      f32x4 v = *(const f32x4*)(f32 + (int64_t)(r0 + row) * C + c0 + c4);
#pragma unroll
      for (int j = 0; j < 4; j++) tile[c4 + j][row] = f2bf(v[j]);
    }
  }
  __syncthreads();
  // write 16B/lane contiguous
  const int rr8 = (tid & 7) * 8, cc = tid >> 3;
#pragma unroll
  for (int ci = 0; ci < 2; ci++) {
    const int col = cc + ci * 32;
    *(u16x8*)(dst + (int64_t)(c0 + col) * R + r0 + rr8) = *(const u16x8*)&tile[col][rr8];
  }
}

// ---------------- GEMM v4: BK=64, global_load_lds, XOR chunk swizzle ------
// __launch_bounds__(256,4): 4 blocks/CU. Round-4 verified; all source-level
// pipelining variants regressed (rounds 1,2,3,6); split-K atomics >2 slices
// regressed (round 7: cross-XCD RMW doubles HBM writes).
// EPI_KV: fused KV epilogue -- K-half (n0<1024) row-major to KVb; V-half
// writes TRANSPOSED into Vt[b][c][k] via packed 8B stores (acc[i][j][0..3]
// are 4 consecutive k at one column c) -> vtrans dispatch eliminated.
// SPLITK=2: no-atomic K-split; slice z stores plain f32 to (z? Cv2 : Cv),
// combined later by ff2_reduce (avoids cross-XCD atomic RMW).
#define BM 128
#define BN 128
#define BK 64

enum { EPI_NONE = 0, EPI_BIAS_RES = 1, EPI_BIAS_GELU = 2, EPI_KV = 3 };

template <int EPI, int RESF32, int OUTF32, int SPLITK>
__device__ __forceinline__ void gemm_body(
    const uint16_t* __restrict__ A, const uint16_t* __restrict__ Bt,
    void* __restrict__ Cv, void* __restrict__ Cv2,
    const uint16_t* __restrict__ bias,
    const void* __restrict__ resid, int M, int N, int K_total,
    int m0, int n0, int zslice, uint16_t* As, uint16_t* Bs) {
  const int tid = threadIdx.x;
  const int w = tid >> 6, l = tid & 63;
  const int wu = __builtin_amdgcn_readfirstlane(w);
  const int wm = (w >> 1) * 64, wn = (w & 1) * 64;
  const int ls = l & 15, lg = l >> 4;
  const int K = (SPLITK > 1) ? (K_total / SPLITK) : K_total;
  const int kof = (SPLITK > 1) ? zslice * K : 0;

  const int sr = 8 * w + (l >> 3);
  const int koff = (((l & 7) ^ ((l >> 3) & 7)) * 8);
  const uint16_t* Ag = A + (int64_t)(m0 + sr) * K_total + kof + koff;
  const uint16_t* Bg = Bt + (int64_t)(n0 + sr) * K_total + kof + koff;
  const int64_t rstep = (int64_t)32 * K_total;

  uint16_t* lA = As + wu * 512;
  uint16_t* lB = Bs + wu * 512;

  f32x4 acc[4][4] = {};

  for (int kb = 0; kb < K; kb += BK) {
    __syncthreads();
#pragma unroll
    for (int r = 0; r < 4; r++) {
      gload16(Ag + r * rstep + kb, lA + r * 2048);
      gload16(Bg + r * rstep + kb, lB + r * 2048);
    }
    __syncthreads();
#pragma unroll
    for (int kk = 0; kk < 2; kk++) {
      s16x8 af[4], bfr[4];
#pragma unroll
      for (int i = 0; i < 4; i++) {
        const int row = wm + i * 16 + ls;
        af[i] = *(const s16x8*)&As[row * 64 + (((kk * 4 + lg) ^ (ls & 7)) * 8)];
      }
#pragma unroll
      for (int j = 0; j < 4; j++) {
        const int row = wn + j * 16 + ls;
        bfr[j] = *(const s16x8*)&Bs[row * 64 + (((kk * 4 + lg) ^ (ls & 7)) * 8)];
      }
#pragma unroll
      for (int i = 0; i < 4; i++)
#pragma unroll
        for (int j = 0; j < 4; j++)
          acc[i][j] = __builtin_amdgcn_mfma_f32_16x16x32_bf16(af[i], bfr[j], acc[i][j], 0, 0, 0);
    }
  }

  if constexpr (EPI == EPI_KV) {
    if (n0 >= 1024) {
      // V-half: transposed packed store. b/k from row (tile never crosses
      // batch: 2048 % 128 == 0); 4 acc elems (rr) = 4 consecutive k.
      uint16_t* VtB = (uint16_t*)Cv2 + (int64_t)(m0 >> 11) * 2097152;
#pragma unroll
      for (int i = 0; i < 4; i++) {
        const int k0 = (m0 & 2047) + wm + i * 16 + lg * 4;
#pragma unroll
        for (int j = 0; j < 4; j++) {
          const int c = n0 - 1024 + wn + j * 16 + ls;
          uint2 pk;
          pk.x = pkbf(acc[i][j][0], acc[i][j][1]);
          pk.y = pkbf(acc[i][j][2], acc[i][j][3]);
          *(uint2*)(VtB + (int64_t)c * 2048 + k0) = pk;
        }
      }
    } else {
      // K-half: row-major bf16 into KVb (stride N=2048)
#pragma unroll
      for (int i = 0; i < 4; i++)
#pragma unroll
        for (int rr = 0; rr < 4; rr++) {
          const int64_t row = m0 + wm + i * 16 + lg * 4 + rr;
#pragma unroll
          for (int j = 0; j < 4; j++) {
            const int col = n0 + wn + j * 16 + ls;
            ((uint16_t*)Cv)[row * N + col] = f2bf(acc[i][j][rr]);
          }
        }
    }
    return;
  }

#pragma unroll
  for (int i = 0; i < 4; i++) {
#pragma unroll
    for (int rr = 0; rr < 4; rr++) {
      const int64_t row = m0 + wm + i * 16 + lg * 4 + rr;
#pragma unroll
      for (int j = 0; j < 4; j++) {
        const int col = n0 + wn + j * 16 + ls;
        float v = acc[i][j][rr];
        if (EPI == EPI_BIAS_RES) {
          const float rv = RESF32 ? ((const float*)resid)[row * N + col]
                                  : bf2f(((const uint16_t*)resid)[row * N + col]);
          v += bf2f(bias[col]) + rv;
        } else if (EPI == EPI_BIAS_GELU) {
          v += bf2f(bias[col]);
          v = gelu_exactf(v);  // exact GELU, fast erf
        }
        if (SPLITK > 1) {
          float* Co = (float*)(zslice ? Cv2 : Cv);
          Co[row * N + col] = v;  // plain f32 slice store (no atomics)
        } else if (OUTF32)
          ((float*)Cv)[row * N + col] = v;
        else
          ((uint16_t*)Cv)[row * N + col] = f2bf(v);
      }
    }
  }
}

template <int EPI, int RESF32, int OUTF32, int SPLITK>
__global__ __launch_bounds__(256, 4) void gemm_single(
    const uint16_t* __restrict__ A, const uint16_t* __restrict__ Bt,
    void* __restrict__ Cv, void* __restrict__ Cv2,
    const uint16_t* __restrict__ bias,
    const void* __restrict__ resid, int M, int N, int K_total) {
  __shared__ alignas(16) uint16_t As[BM * BK];
  __shared__ alignas(16) uint16_t Bs[BN * BK];
  gemm_body<EPI, RESF32, OUTF32, SPLITK>(A, Bt, Cv, Cv2, bias, resid, M, N, K_total,
                                         blockIdx.x * BM, blockIdx.y * BN,
                                         (int)blockIdx.z, As, Bs);
}

// grouped Q-proj + KV-proj: blocks [0,256) Q, [256,1280) KV. K=1024 both.
// KV uses fused EPI_KV epilogue (K -> KVb, V -> Vt transposed).
__global__ __launch_bounds__(256, 4) void gemm_qkv(
    const uint16_t* __restrict__ xA, const uint16_t* __restrict__ WqT,
    uint16_t* __restrict__ Qb,
    const uint16_t* __restrict__ ctxA, const uint16_t* __restrict__ KVWt,
    uint16_t* __restrict__ KVb, uint16_t* __restrict__ Vt) {
  __shared__ alignas(16) uint16_t As[BM * BK];
  __shared__ alignas(16) uint16_t Bs[BN * BK];
  const int id = blockIdx.x;
  if (id < 256) {
    gemm_body<EPI_NONE, 0, 0, 1>(xA, WqT, Qb, nullptr, nullptr, nullptr, 4096, 1024, 1024,
                                 (id & 31) * BM, (id >> 5) * BN, 0, As, Bs);
  } else {
    const int t = id - 256;
    gemm_body<EPI_KV, 0, 0, 1>(ctxA, KVWt, KVb, Vt, nullptr, nullptr, 8192, 2048, 1024,
                               (t & 63) * BM, (t >> 6) * BN, 0, As, Bs);
  }
}

// ---- FF2 finish: d_out = z0(d_out) + z1(P1f) + b2 + X1, f32, vectorized ---
__global__ __launch_bounds__(256) void ff2_reduce(
    float* __restrict__ dout, const float* __restrict__ p1,
    const uint16_t* __restrict__ X1, const uint16_t* __restrict__ b2) {
  const int64_t i0 = ((int64_t)blockIdx.x * 256 + threadIdx.x) * 8;
  f32x4 d0 = *(const f32x4*)(dout + i0), d1 = *(const f32x4*)(dout + i0 + 4);
  f32x4 q0 = *(const f32x4*)(p1 + i0),  q1 = *(const f32x4*)(p1 + i0 + 4);
  u16x8 x = *(const u16x8*)(X1 + i0);
  u16x8 bb = *(const u16x8*)(b2 + (i0 & 1023));
  f32x4 r0, r1;
#pragma unroll
  for (int e = 0; e < 4; e++) {
    r0[e] = d0[e] + q0[e] + bf2f(x[e]) + bf2f(bb[e]);
    r1[e] = d1[e] + q1[e] + bf2f(x[e + 4]) + bf2f(bb[e + 4]);
  }
  *(f32x4*)(dout + i0) = r0;
  *(f32x4*)(dout + i0 + 4) = r1;
}

// ---------------- flash cross-attention v7 (round-5 proven) ----------------
// dbuf K/V -> one barrier/tile; ones-MFMA row-sum in epilogue lane layout;
// setprio around MFMA clusters (2 independent blocks/CU).
#define KLD 72
#define PLD 72

__global__ __launch_bounds__(256, 2) void attn_kernel(
    const uint16_t* __restrict__ Q,   // [B*1024][1024]
    const uint16_t* __restrict__ KV,  // [B*2048][2048]; cols 0..1023 = K
    const uint16_t* __restrict__ Vt,  // [B][1024 (h*64+d)][2048 (key)]
    uint16_t* __restrict__ O) {       // [B*1024][1024]
  __shared__ alignas(16) uint16_t Ks[2][64 * KLD];
  __shared__ alignas(16) uint16_t Vts[2][64 * KLD];
  __shared__ alignas(16) uint16_t Ps[8][16 * PLD];  // [w*2+qq]

  const int tid = threadIdx.x;
  const int w = tid >> 6, l = tid & 63;
  const int ls = l & 15, lg = l >> 4;

  const int blk = blockIdx.x;
  const int bh = blk & 63;   // XCD = bh%8 for all 8 q-blocks of this (b,h)
  const int qb = blk >> 6;   // 0..7
  const int h = bh & 15, b = bh >> 4;

  const int64_t qrow0 = (int64_t)b * 1024 + qb * 128;
  const int hoff = h * 64;
  const uint16_t* Vtb = Vt + (int64_t)b * 1024 * 2048;

  const float sc = 0.125f * 1.4426950408889634f;  // scale * log2(e)

  s16x8 qf[2][2];
#pragma unroll
  for (int qq = 0; qq < 2; qq++)
#pragma unroll
    for (int ks = 0; ks < 2; ks++) {
      s16x8 r = *(const s16x8*)(Q + (qrow0 + w * 32 + qq * 16 + ls) * 1024 + hoff + ks * 32 + lg * 8);
#pragma unroll
      for (int j = 0; j < 8; j++)
        qf[qq][ks][j] = (short)f2bf(bf2f((uint16_t)r[j]) * sc);
    }

  // ones fragment: bf16 1.0 in all 8 slots
  s16x8 onef;
#pragma unroll
  for (int j = 0; j < 8; j++) onef[j] = (short)0x3F80;

  f32x4 oacc[2][4] = {};
  f32x4 lsacc[2] = {};  // row-sum accumulator (ones-MFMA), C-layout

  const int srow = tid >> 3;      // 0..31
  const int sc8 = (tid & 7) * 8;  // 0..56
  const uint16_t* Kg = KV + ((int64_t)b * 2048 + srow) * 2048 + hoff + sc8;
  const uint16_t* Vg = Vtb + (int64_t)(hoff + srow) * 2048 + sc8;

  s16x8 rk0 = *(const s16x8*)(Kg);
  s16x8 rk1 = *(const s16x8*)(Kg + (int64_t)32 * 2048);
  s16x8 rv0 = *(const s16x8*)(Vg);
  s16x8 rv1 = *(const s16x8*)(Vg + (int64_t)32 * 2048);

  for (int kt = 0; kt < 2048; kt += 64) {
    const int bi = (kt >> 6) & 1;
    *(s16x8*)&Ks[bi][srow * KLD + sc8] = rk0;
    *(s16x8*)&Ks[bi][(srow + 32) * KLD + sc8] = rk1;
    *(s16x8*)&Vts[bi][srow * KLD + sc8] = rv0;
    *(s16x8*)&Vts[bi][(srow + 32) * KLD + sc8] = rv1;
    const int ktn = kt + 64;
    if (ktn < 2048) {
      rk0 = *(const s16x8*)(Kg + (int64_t)ktn * 2048);
      rk1 = *(const s16x8*)(Kg + (int64_t)(ktn + 32) * 2048);
      rv0 = *(const s16x8*)(Vg + ktn);
      rv1 = *(const s16x8*)(Vg + ktn + (int64_t)32 * 2048);
    }
    __syncthreads();  // single barrier per tile (dbuf makes pre-write sync redundant)

    f32x4 st[2][4];
    __builtin_amdgcn_s_setprio(1);
#pragma unroll
    for (int jn = 0; jn < 4; jn++) {
      f32x4 z = {0.f, 0.f, 0.f, 0.f};
      st[0][jn] = z; st[1][jn] = z;
#pragma unroll
      for (int ks = 0; ks < 2; ks++) {
        s16x8 kf = *(const s16x8*)&Ks[bi][(jn * 16 + ls) * KLD + ks * 32 + lg * 8];
        st[0][jn] = __builtin_amdgcn_mfma_f32_16x16x32_bf16(kf, qf[0][ks], st[0][jn], 0, 0, 0);
        st[1][jn] = __builtin_amdgcn_mfma_f32_16x16x32_bf16(kf, qf[1][ks], st[1][jn], 0, 0, 0);
      }
    }
    __builtin_amdgcn_s_setprio(0);

#pragma unroll
    for (int qq = 0; qq < 2; qq++)
#pragma unroll
      for (int jn = 0; jn < 4; jn++) {
        const float p0 = exp2f(st[qq][jn][0]);
        const float p1 = exp2f(st[qq][jn][1]);
        const float p2 = exp2f(st[qq][jn][2]);
        const float p3 = exp2f(st[qq][jn][3]);
        uint2 pk; pk.x = pkbf(p0, p1); pk.y = pkbf(p2, p3);
        *(uint2*)&Ps[w * 2 + qq][ls * PLD + jn * 16 + lg * 4] = pk;
      }

    __builtin_amdgcn_s_setprio(1);
#pragma unroll
    for (int ks = 0; ks < 2; ks++) {
      s16x8 pf0 = *(const s16x8*)&Ps[w * 2 + 0][ls * PLD + ks * 32 + lg * 8];
      s16x8 pf1 = *(const s16x8*)&Ps[w * 2 + 1][ls * PLD + ks * 32 + lg * 8];
#pragma unroll
      for (int jn = 0; jn < 4; jn++) {
        s16x8 vf = *(const s16x8*)&Vts[bi][(jn * 16 + ls) * KLD + ks * 32 + lg * 8];
        oacc[0][jn] = __builtin_amdgcn_mfma_f32_16x16x32_bf16(pf0, vf, oacc[0][jn], 0, 0, 0);
        oacc[1][jn] = __builtin_amdgcn_mfma_f32_16x16x32_bf16(pf1, vf, oacc[1][jn], 0, 0, 0);
      }
      // row-sum: D[r][c] = sum_k P[r,k]*1; lane (ls,lg) gets rowsum for
      // q = lg*4+rr -- exactly the epilogue's lane mapping.
      lsacc[0] = __builtin_amdgcn_mfma_f32_16x16x32_bf16(pf0, onef, lsacc[0], 0, 0, 0);
      lsacc[1] = __builtin_amdgcn_mfma_f32_16x16x32_bf16(pf1, onef, lsacc[1], 0, 0, 0);
    }
    __builtin_amdgcn_s_setprio(0);
  }

#pragma unroll
  for (int qq = 0; qq < 2; qq++) {
#pragma unroll
    for (int rr = 0; rr < 4; rr++) {
      const float inv = 1.0f / lsacc[qq][rr];
      const int64_t row = qrow0 + w * 32 + qq * 16 + lg * 4 + rr;
#pragma unroll
      for (int jn = 0; jn < 4; jn++)
        O[row * 1024 + hoff + jn * 16 + ls] = f2bf(oacc[qq][jn][rr] * inv);
    }
  }
}

// ---------------- host ----------------
extern "C" void kernel_launch(void* const* d_in, const int* in_sizes, int n_in,
                              void* d_out, int out_size, void* d_ws, size_t ws_size,
                              hipStream_t stream) {
  const void* x_raw   = d_in[0];
  const void* ctx_raw = d_in[1];
  const void* Wq_raw  = d_in[2];
  const void* Wk_raw  = d_in[3];
  const void* Wv_raw  = d_in[4];
  const void* Wo_raw  = d_in[5];
  const void* bo_raw  = d_in[6];
  const void* W1_raw  = d_in[7];
  const void* b1_raw  = d_in[8];
  const void* W2_raw  = d_in[9];
  const void* b2_raw  = d_in[10];

  const int64_t Mi = 1 << 20;
  uint16_t* ws   = (uint16_t*)d_ws;
  uint16_t* WqT  = ws;                  // [0,1M)   dead after qkv
  uint16_t* KVWt = ws + 1 * Mi;         // [1M,3M)  dead after qkv
  uint16_t* WoT  = ws + 3 * Mi;         // [3M,4M)  dead after out-proj
  uint16_t* W1T  = ws + 4 * Mi;         // [4M,8M)  dead after FF1
  float*    P1f  = (float*)ws;          // [0,8M) u16 = 16MB; alias WqT..W1T
                                        //   (all dead by FF2 launch)
  uint16_t* W2T  = ws + 8 * Mi;         // [8M,12M)  [1024][4096]
  uint16_t* bob  = ws + 12 * Mi;
  uint16_t* b1b  = ws + 12 * Mi + 1024;
  uint16_t* b2b  = ws + 12 * Mi + 5120;
  uint16_t* xb   = ws + 13 * Mi;        // [13M,17M) dead after Q-proj
  uint16_t* AO   = ws + 13 * Mi;        // alias xb (born in attention)
  uint16_t* ctxb = ws + 17 * Mi;        // [17M,25M) dead after KV-proj
  uint16_t* X1   = ws + 17 * Mi;        // alias ctxb (born after attention)
  uint16_t* Qb   = ws + 25 * Mi;        // [25M,29M)
  uint16_t* KVb  = ws + 29 * Mi;        // [29M,45M) [8192][2048]; V-half unused
  uint16_t* Hb   = ws + 29 * Mi;        // alias KVb (born at FF1)
  // Vt lives in d_out (16MB): written by KV-proj (transposed V), read by
  // attn, then overwritten by FF2-z0 plain stores. No zeroing needed.
  uint16_t* Vt   = (uint16_t*)d_out;
  // peak ws: 45M elements = 90 MB

  const dim3 tb(256);
  // one fused prep dispatch (vectorized): converts + 6 transposes
  prep_all<<<dim3(6147), tb, 0, stream>>>(
      x_raw, ctx_raw, bo_raw, b1_raw, b2_raw,
      Wq_raw, Wk_raw, Wv_raw, Wo_raw, W1_raw, W2_raw,
      xb, ctxb, bob, b1b, b2b,
      WqT, KVWt, KVWt + Mi, WoT, W1T, W2T);

  // grouped Q-proj + fused KV-proj (1280 blocks); V written transposed
  gemm_qkv<<<dim3(1280), tb, 0, stream>>>(xb, WqT, Qb, ctxb, KVWt, KVb, Vt);

  attn_kernel<<<dim3(512), tb, 0, stream>>>(Qb, KVb, Vt, AO);

  // out-proj + bias + residual(x, fp32 direct)
  gemm_single<EPI_BIAS_RES, 1, 0, 1><<<dim3(32, 8), tb, 0, stream>>>(
      AO, WoT, X1, nullptr, bob, x_raw, 4096, 1024, 1024);
  // FF1 + bias + exact GELU (fast erf)
  gemm_single<EPI_BIAS_GELU, 0, 0, 1><<<dim3(32, 32), tb, 0, stream>>>(
      X1, W1T, Hb, nullptr, b1b, nullptr, 4096, 4096, 1024);
  // FF2 split-K2, NO atomics: z0 -> d_out (plain f32), z1 -> P1f partial
  gemm_single<EPI_NONE, 0, 1, 2><<<dim3(32, 8, 2), tb, 0, stream>>>(
      Hb, W2T, d_out, P1f, nullptr, nullptr, 4096, 1024, 4096);
  // fused finish: d_out = z0 + z1 + b2 + X1
  ff2_reduce<<<dim3(2048), tb, 0, stream>>>((float*)d_out, P1f, X1, b2b);
}